// Round 7
// baseline (129.763 us; speedup 1.0000x reference)
//
#include <hip/hip_runtime.h>
#include <math.h>

#define HF 37
#define WF 50
#define CC 512
#define POOLD 7
#define SAMPD 14

typedef float nfloat4 __attribute__((ext_vector_type(4)));

__device__ __forceinline__ float4 lerp4(float4 a, float4 b, float t) {
    float4 r;
    r.x = a.x + t * (b.x - a.x);
    r.y = a.y + t * (b.y - a.y);
    r.z = a.z + t * (b.z - a.z);
    r.w = a.w + t * (b.w - a.w);
    return r;
}

__device__ __forceinline__ float4 max4(float4 a, float4 b) {
    float4 r;
    r.x = fmaxf(a.x, b.x);
    r.y = fmaxf(a.y, b.y);
    r.z = fmaxf(a.z, b.z);
    r.w = fmaxf(a.w, b.w);
    return r;
}

__device__ __forceinline__ void store_nt4(float* p, float4 v) {
    nfloat4 nv;
    nv.x = v.x; nv.y = v.y; nv.z = v.z; nv.w = v.w;
    __builtin_nontemporal_store(nv, (nfloat4*)p);
}

// One 2x2-sample bin, deduplicated loads, fully straight-line.
// RC: row-share case (0: both sample rows use same feat-row pair -> 2 rows;
//     1: middle row shared -> 3 rows; 2: general -> 4 rows)
// CCASE: col-share case (0: both sample cols use same feat-col pair -> 2 cols;
//     1: middle col shared -> 3 cols; 2: general -> 4 cols)
// All NR*NC loads are independent -> issued together, one wait.
template <int RC, int CCASE>
__device__ __forceinline__ void do_bin(const float* __restrict__ pbase,
                                       float* __restrict__ optr,
                                       int ro0, int ro1, int ro2, int ro3,
                                       int ca0, int ca1, int cb0, int cb1,
                                       float wya, float wyb, float wxa, float wxb)
{
    constexpr int NR = RC + 2;
    constexpr int NC = CCASE + 2;
    int rofs[NR];
    rofs[0] = ro0; rofs[1] = ro1;
    if constexpr (RC == 1) { rofs[2] = ro3; }
    if constexpr (RC == 2) { rofs[2] = ro2; rofs[3] = ro3; }
    int cofs[NC];
    cofs[0] = ca0; cofs[1] = ca1;
    if constexpr (CCASE == 1) { cofs[2] = cb1; }
    if constexpr (CCASE == 2) { cofs[2] = cb0; cofs[3] = cb1; }

    float4 cell[NR][NC];
    #pragma unroll
    for (int r = 0; r < NR; ++r) {
        #pragma unroll
        for (int c = 0; c < NC; ++c) {
            cell[r][c] = *(const float4*)(pbase + rofs[r] + cofs[c]);
        }
    }

    // vertical reduction: sample-row a uses rows (0,1); b uses (NR-2,NR-1)
    float4 vA[NC], vB[NC];
    #pragma unroll
    for (int c = 0; c < NC; ++c) {
        vA[c] = lerp4(cell[0][c],    cell[1][c],    wya);
        vB[c] = lerp4(cell[NR-2][c], cell[NR-1][c], wyb);
    }

    // horizontal: sample-col a uses cols (0,1); b uses (NC-2,NC-1)
    float4 s0 = lerp4(vA[0],    vA[1],    wxa);
    float4 s1 = lerp4(vA[NC-2], vA[NC-1], wxb);
    float4 s2 = lerp4(vB[0],    vB[1],    wxa);
    float4 s3 = lerp4(vB[NC-2], vB[NC-1], wxb);

    store_nt4(optr, max4(max4(s0, s1), max4(s2, s3)));
}

// One block per (roi, py, px) bin. 128 threads * float4 = 512 channels.
__global__ __launch_bounds__(128, 4) void roipool_kernel(
    const float* __restrict__ feat,    // [HF, WF, CC]
    const float* __restrict__ rois,    // [N, 4] (x1,y1,x2,y2)
    const int*   __restrict__ im_size, // [2] (h, w)
    float*       __restrict__ out,     // [N, 7, 7, CC]
    int N)
{
    int bid = blockIdx.x;
    int n   = bid / (POOLD * POOLD);
    if (n >= N) return;
    int rem = bid - n * (POOLD * POOLD);
    int py  = rem / POOLD;
    int px  = rem - py * POOLD;

    float h = (float)im_size[0];
    float w = (float)im_size[1];
    float bx1 = rois[4 * n + 0];
    float by1 = rois[4 * n + 1];
    float bx2 = rois[4 * n + 2];
    float by2 = rois[4 * n + 3];
    float ny1 = by1 / h, nx1 = bx1 / w;
    float ny2 = by2 / h, nx2 = bx2 / w;

    const float inv = 1.0f / (float)(SAMPD - 1);

    // two sample rows (block-uniform)
    float ysa = (ny1 + (ny2 - ny1) * ((float)(2 * py) * inv)) * (float)(HF - 1);
    float ysb = (ny1 + (ny2 - ny1) * ((float)(2 * py + 1) * inv)) * (float)(HF - 1);
    ysa = fminf(fmaxf(ysa, 0.0f), (float)(HF - 1));
    ysb = fminf(fmaxf(ysb, 0.0f), (float)(HF - 1));
    float ya0 = floorf(ysa), yb0 = floorf(ysb);
    float wya = ysa - ya0,  wyb = ysb - yb0;
    int iya = __builtin_amdgcn_readfirstlane((int)ya0);
    int iyb = __builtin_amdgcn_readfirstlane((int)yb0);
    int ro0 = iya * (WF * CC);
    int ro1 = min(iya + 1, HF - 1) * (WF * CC);
    int ro2 = iyb * (WF * CC);
    int ro3 = min(iyb + 1, HF - 1) * (WF * CC);

    // two sample cols (block-uniform)
    float xsa = (nx1 + (nx2 - nx1) * ((float)(2 * px) * inv)) * (float)(WF - 1);
    float xsb = (nx1 + (nx2 - nx1) * ((float)(2 * px + 1) * inv)) * (float)(WF - 1);
    xsa = fminf(fmaxf(xsa, 0.0f), (float)(WF - 1));
    xsb = fminf(fmaxf(xsb, 0.0f), (float)(WF - 1));
    float xa0 = floorf(xsa), xb0 = floorf(xsb);
    float wxa = xsa - xa0,  wxb = xsb - xb0;
    int ixa = __builtin_amdgcn_readfirstlane((int)xa0);
    int ixb = __builtin_amdgcn_readfirstlane((int)xb0);
    int ca0 = ixa * CC;
    int ca1 = min(ixa + 1, WF - 1) * CC;
    int cb0 = ixb * CC;
    int cb1 = min(ixb + 1, WF - 1) * CC;

    const float* pbase = feat + (size_t)threadIdx.x * 4;
    float* optr = out + (size_t)bid * CC + (size_t)threadIdx.x * 4;

    int rcase = (ro2 == ro0) ? 0 : ((ro2 == ro1) ? 1 : 2);
    int ccase = (cb0 == ca0) ? 0 : ((cb0 == ca1) ? 1 : 2);

    switch (rcase * 3 + ccase) {
        case 0: do_bin<0,0>(pbase, optr, ro0,ro1,ro2,ro3, ca0,ca1,cb0,cb1, wya,wyb,wxa,wxb); break;
        case 1: do_bin<0,1>(pbase, optr, ro0,ro1,ro2,ro3, ca0,ca1,cb0,cb1, wya,wyb,wxa,wxb); break;
        case 2: do_bin<0,2>(pbase, optr, ro0,ro1,ro2,ro3, ca0,ca1,cb0,cb1, wya,wyb,wxa,wxb); break;
        case 3: do_bin<1,0>(pbase, optr, ro0,ro1,ro2,ro3, ca0,ca1,cb0,cb1, wya,wyb,wxa,wxb); break;
        case 4: do_bin<1,1>(pbase, optr, ro0,ro1,ro2,ro3, ca0,ca1,cb0,cb1, wya,wyb,wxa,wxb); break;
        case 5: do_bin<1,2>(pbase, optr, ro0,ro1,ro2,ro3, ca0,ca1,cb0,cb1, wya,wyb,wxa,wxb); break;
        case 6: do_bin<2,0>(pbase, optr, ro0,ro1,ro2,ro3, ca0,ca1,cb0,cb1, wya,wyb,wxa,wxb); break;
        case 7: do_bin<2,1>(pbase, optr, ro0,ro1,ro2,ro3, ca0,ca1,cb0,cb1, wya,wyb,wxa,wxb); break;
        default: do_bin<2,2>(pbase, optr, ro0,ro1,ro2,ro3, ca0,ca1,cb0,cb1, wya,wyb,wxa,wxb); break;
    }
}

extern "C" void kernel_launch(void* const* d_in, const int* in_sizes, int n_in,
                              void* d_out, int out_size, void* d_ws, size_t ws_size,
                              hipStream_t stream) {
    const float* feat    = (const float*)d_in[0];   // [1,37,50,512]
    const float* rois    = (const float*)d_in[1];   // [N,4]
    const int*   im_size = (const int*)d_in[2];     // [2]
    float* out = (float*)d_out;

    int N = in_sizes[1] / 4;
    int nblocks = N * POOLD * POOLD;
    roipool_kernel<<<nblocks, 128, 0, stream>>>(feat, rois, im_size, out, N);
}